// Round 1
// 556.516 us; speedup vs baseline: 1.0063x; 1.0063x over previous
//
#include <hip/hip_runtime.h>

// Output layout (floats): x_top[262144] | y_min[16384] | z_val[393216] | z_idx[393216]
#define OUT_X  0
#define OUT_Y  262144
#define OUT_ZV 278528
#define OUT_ZI 671744

// Block partition: [0,256) = y; remaining 49152 blocks interleave 2 z + 1 x per group.
#define YB 256
#define NG 16384   // groups; z blocks = 2*NG = 32768, x blocks = NG = 16384

// native vector type for nontemporal builtin (HIP's float4 is a class)
typedef float vf4 __attribute__((ext_vector_type(4)));

__device__ __forceinline__ float4 ldnt4(const float4* p) {
    vf4 v = __builtin_nontemporal_load((const vf4*)p);
    return make_float4(v.x, v.y, v.z, v.w);
}

__device__ __forceinline__ int imin(int a, int b) { return a < b ? a : b; }

// ---------------- helpers: x (float top-4) ----------------

__device__ __forceinline__ void bub4(float &a0, float &a1, float &a2, float &a3, float v) {
    float r;
    r = fminf(a0, v); a0 = fmaxf(a0, v); v = r;
    r = fminf(a1, v); a1 = fmaxf(a1, v); v = r;
    r = fminf(a2, v); a2 = fmaxf(a2, v); v = r;
    a3 = fmaxf(a3, v);
}

// merge two sorted-desc 4-lists -> sorted-desc top-4 of union (bitonic)
__device__ __forceinline__ void merge4(float &a0, float &a1, float &a2, float &a3,
                                       float b0, float b1, float b2, float b3) {
    float m0 = fmaxf(a0, b3), m1 = fmaxf(a1, b2), m2 = fmaxf(a2, b1), m3 = fmaxf(a3, b0);
    float e0 = fmaxf(m0, m2), e2 = fminf(m0, m2);
    float e1 = fmaxf(m1, m3), e3 = fminf(m1, m3);
    a0 = fmaxf(e0, e1); a1 = fminf(e0, e1);
    a2 = fmaxf(e2, e3); a3 = fminf(e2, e3);
}

// ---------------- helpers: y (float4 min) ----------------

__device__ __forceinline__ float4 min4(float4 a, float4 b) {
    return make_float4(fminf(a.x, b.x), fminf(a.y, b.y), fminf(a.z, b.z), fminf(a.w, b.w));
}

// ---------------- helpers: z (float top-3 values, then exact index recovery) ----------------

__device__ __forceinline__ void ins3f(float &k0, float &k1, float &k2, float v) {
    float t;
    t = fminf(k0, v); k0 = fmaxf(k0, v); v = t;
    t = fminf(k1, v); k1 = fmaxf(k1, v); v = t;
    k2 = fmaxf(k2, v);
}

__device__ __forceinline__ void cef(float &a, float &b) {
    float hi = fmaxf(a, b), lo = fminf(a, b);
    a = hi; b = lo;
}

// merge two sorted-desc 3-lists -> sorted-desc top-3 of union (bitonic)
__device__ __forceinline__ void merge3f(float &a0, float &a1, float &a2,
                                        float b0, float b1, float b2) {
    float m0 = fmaxf(a0, b2), m1 = fmaxf(a1, b1), m2 = fmaxf(a2, b0);
    cef(m0, m1); cef(m1, m2); cef(m0, m1);
    a0 = m0; a1 = m1; a2 = m2;
}

// ---------------- fused kernel ----------------

__global__ __launch_bounds__(256) void fused_topk_kernel(const float* __restrict__ x,
                                                         const float* __restrict__ y,
                                                         const float* __restrict__ z,
                                                         float* __restrict__ out) {
    const int bid = blockIdx.x;
    const int tid = threadIdx.x;

    if (bid < YB) {
        // ---- y: min over dim 2 of [8,32,2048,64]; one block per (b0,b1) pair ----
        const int pair = bid;
        const int c4 = tid & 15;          // float4 column
        const int rg = tid >> 4;          // row group 0..15
        const float4* base = (const float4*)(y + (size_t)pair * 2048 * 64);

        const float INF = 3.402823466e38f;
        float4 m = make_float4(INF, INF, INF, INF);
        #pragma unroll 8
        for (int r = rg; r < 2048; r += 16) {
            m = min4(m, ldnt4(base + r * 16 + c4));
        }

        __shared__ float4 red[256];       // 4 KiB
        red[tid] = m;
        __syncthreads();
        #pragma unroll
        for (int s = 128; s >= 16; s >>= 1) {
            if (tid < s) red[tid] = min4(red[tid], red[tid + s]);
            __syncthreads();
        }
        if (tid < 16) {
            ((float4*)(out + OUT_Y + pair * 64))[tid] = red[tid];
        }
        return;
    }

    // Interleaved z/x region: group g = (2 z-blocks, 1 x-block)
    const unsigned b = (unsigned)(bid - YB);
    const unsigned g = b / 3u;
    const unsigned r3 = b - g * 3u;

    if (r3 < 2u) {
        // ---- z: top-3 vals+idx over rows of 512; one wave per row ----
        const int zb   = (int)(2u * g + r3);
        const int lane = tid & 63;
        const int row  = zb * 4 + (tid >> 6);
        const float4* r4 = (const float4*)(z + (size_t)row * 512);

        float4 p = ldnt4(r4 + lane);
        float4 q = ldnt4(r4 + lane + 64);

        // Phase 1: wave top-3 VALUES (cheap single-op float min/max)
        const float NINF = -3.402823466e38f;
        float a0 = NINF, a1 = NINF, a2 = NINF;
        float b0 = NINF, b1 = NINF, b2 = NINF;
        ins3f(a0, a1, a2, p.x); ins3f(b0, b1, b2, q.x);
        ins3f(a0, a1, a2, p.y); ins3f(b0, b1, b2, q.y);
        ins3f(a0, a1, a2, p.z); ins3f(b0, b1, b2, q.z);
        ins3f(a0, a1, a2, p.w); ins3f(b0, b1, b2, q.w);
        merge3f(a0, a1, a2, b0, b1, b2);

        #pragma unroll
        for (int m = 1; m < 64; m <<= 1) {
            float s0 = __shfl_xor(a0, m, 64);
            float s1 = __shfl_xor(a1, m, 64);
            float s2 = __shfl_xor(a2, m, 64);
            merge3f(a0, a1, a2, s0, s1, s2);
        }
        // all lanes now hold identical a0 >= a1 >= a2

        // Phase 2: exact index recovery, tie-stable (value desc, index asc).
        // Round j: min global index with val == t_j and idx > floor_j, where
        // floor_j chains the previous winner when t_j repeats.
        const int gA = 4 * lane;          // global idx of p slots; q slots at gA+256
        const int BIG = 0x7fffffff;

        #define ZROUND(T, FLOOR, WOUT)                                               \
        {                                                                            \
            const float t_ = (T); const int fl_ = (FLOOR);                           \
            int cand = BIG;                                                          \
            cand = imin(cand, (p.x == t_ && (gA + 0)   > fl_) ? (gA + 0)   : BIG);   \
            cand = imin(cand, (p.y == t_ && (gA + 1)   > fl_) ? (gA + 1)   : BIG);   \
            cand = imin(cand, (p.z == t_ && (gA + 2)   > fl_) ? (gA + 2)   : BIG);   \
            cand = imin(cand, (p.w == t_ && (gA + 3)   > fl_) ? (gA + 3)   : BIG);   \
            cand = imin(cand, (q.x == t_ && (gA + 256) > fl_) ? (gA + 256) : BIG);   \
            cand = imin(cand, (q.y == t_ && (gA + 257) > fl_) ? (gA + 257) : BIG);   \
            cand = imin(cand, (q.z == t_ && (gA + 258) > fl_) ? (gA + 258) : BIG);   \
            cand = imin(cand, (q.w == t_ && (gA + 259) > fl_) ? (gA + 259) : BIG);   \
            _Pragma("unroll")                                                        \
            for (int m = 1; m < 64; m <<= 1) {                                       \
                cand = imin(cand, __shfl_xor(cand, m, 64));                          \
            }                                                                        \
            WOUT = cand;                                                             \
        }

        int w0, w1, w2;
        ZROUND(a0, -1, w0);
        ZROUND(a1, (a1 == a0) ? w0 : -1, w1);
        ZROUND(a2, (a2 == a1) ? w1 : -1, w2);
        #undef ZROUND

        if (lane == 0) {
            float* outv = out + OUT_ZV + (size_t)row * 3;
            float* outi = out + OUT_ZI + (size_t)row * 3;
            outv[0] = a0; outv[1] = a1; outv[2] = a2;
            outi[0] = (float)w0; outi[1] = (float)w1; outi[2] = (float)w2;
        }
    } else {
        // ---- x: top-4 over rows of 1024; one wave per row ----
        const int xb   = (int)g;
        const int lane = tid & 63;
        const int row  = xb * 4 + (tid >> 6);
        const float4* r4 = (const float4*)(x + (size_t)row * 1024);

        float4 v0 = ldnt4(r4 + lane);
        float4 v1 = ldnt4(r4 + lane + 64);
        float4 v2 = ldnt4(r4 + lane + 128);
        float4 v3 = ldnt4(r4 + lane + 192);

        const float NINF = -3.402823466e38f;
        // two independent chains, merged once
        float a0 = NINF, a1 = NINF, a2 = NINF, a3 = NINF;
        float c0 = NINF, c1 = NINF, c2 = NINF, c3 = NINF;
        bub4(a0, a1, a2, a3, v0.x); bub4(c0, c1, c2, c3, v2.x);
        bub4(a0, a1, a2, a3, v0.y); bub4(c0, c1, c2, c3, v2.y);
        bub4(a0, a1, a2, a3, v0.z); bub4(c0, c1, c2, c3, v2.z);
        bub4(a0, a1, a2, a3, v0.w); bub4(c0, c1, c2, c3, v2.w);
        bub4(a0, a1, a2, a3, v1.x); bub4(c0, c1, c2, c3, v3.x);
        bub4(a0, a1, a2, a3, v1.y); bub4(c0, c1, c2, c3, v3.y);
        bub4(a0, a1, a2, a3, v1.z); bub4(c0, c1, c2, c3, v3.z);
        bub4(a0, a1, a2, a3, v1.w); bub4(c0, c1, c2, c3, v3.w);
        merge4(a0, a1, a2, a3, c0, c1, c2, c3);

        #pragma unroll
        for (int m = 1; m < 64; m <<= 1) {
            float s0 = __shfl_xor(a0, m, 64);
            float s1 = __shfl_xor(a1, m, 64);
            float s2 = __shfl_xor(a2, m, 64);
            float s3 = __shfl_xor(a3, m, 64);
            merge4(a0, a1, a2, a3, s0, s1, s2, s3);
        }

        if (lane == 0) {
            ((float4*)(out + OUT_X))[row] = make_float4(a0, a1, a2, a3);
        }
    }
}

extern "C" void kernel_launch(void* const* d_in, const int* in_sizes, int n_in,
                              void* d_out, int out_size, void* d_ws, size_t ws_size,
                              hipStream_t stream) {
    const float* x = (const float*)d_in[0];
    const float* y = (const float*)d_in[1];
    const float* z = (const float*)d_in[2];
    float* out = (float*)d_out;

    fused_topk_kernel<<<YB + 3 * NG, 256, 0, stream>>>(x, y, z, out);
}